// Round 15
// baseline (155.466 us; speedup 1.0000x reference)
//
#include <hip/hip_runtime.h>
#include <cmath>

// SSIM stability loss: 1 - mean(SSIM(x,y)), 11x11 Gaussian (sigma=1.5), zero SAME
// padding, fp32, 32 x 1 x 512 x 512.
//
// R31: forced 16-wave residency WITHOUT spills -- the one untested clean cell.
// Evidence: R24 proved a 1024-thr block is the ONLY config that raises real
// occupancy (15 -> 36.5%); it died to hipcc's default 64-VGPR target (plain
// launch_bounds(1024)) -> 29MB scratch. R29 proved 2x512-thr blocks do NOT
// co-reside (occ stuck 17%) even when LDS/VGPR fit. Fix: launch_bounds(1024,1)
// (MINIMUM occupancy hint) -> VGPR cap 128 (4 waves/SIMD launchability),
// natural ~80 -> spill-free. Structure = R26/R29 proven barrier-free
// per-wave private single-buffer tiles: wave w owns 64-col strip ((w&7)*64)
// x 32-row band (r0 + (w>>3)*32); in-order per-wave DS is the only sync.
// LDS 16 x 7040 = 112.6KB dynamic (attribute path proven R24).
// Cost: BROWS=32 halo 42/32 -> +7.6% total VALU (known from R21/R29).
//
// Inner loop = R19/R25/R26 proven: unscaled sum/diff channels u=x+y, v=x-y
// + squares (2C1/2C2 algebra); 6 aligned ds_read_b128/row; parity-folded
// 12-tap weight vector; 11-deep circular history; fp64 atomic finish.
//
// Predict: VGPR 80-128 & WRITE_SIZE ~16B (if VGPR=64 the hint was ignored,
// test invalid); Occupancy ~35-50%; if per-wave duty scales with 4 waves/
// SIMD: VALUBusy 60-80%, dur 42 -> 28-34us. Spill-free + occ up + dur >=40
// => waves/SIMD definitively refuted; declare structural plateau next round.

#define IMG   512
#define BROWS 32             // rows per wave band
#define NHROW (BROWS + 10)   // 42 H-rows per band
#define NCHUNK 4             // ceil(42/11)
#define CHR   11             // rows per LDS chunk (== history depth)
#define WQUADS 20            // float4 col-quads staged per row per wave (80 cols)
#define WUNITS 40            // v4f units per staged row per wave
#define NQ (CHR * WQUADS)    // 220 quads per chunk per wave
#define WAVE_LDS (CHR * WUNITS)            // 440 v4f units per wave (single buffer)
#define LDS_BYTES (16 * WAVE_LDS * 16)     // 112640
#define NBLOCKS 256
#define NPIX  8388608.0

typedef float v2f __attribute__((ext_vector_type(2)));
typedef float v4f __attribute__((ext_vector_type(4)));

struct GaussW { float w[11]; };

__global__ __launch_bounds__(1024, 1)
void ssim_stream_kernel(const float* __restrict__ x, const float* __restrict__ y,
                        double* __restrict__ acc_ws, unsigned long long* __restrict__ ctr,
                        float* __restrict__ out, GaussW gw) {
    extern __shared__ v4f dsm[];        // [16 waves][CHR][WUNITS]
    __shared__ float wavesum[16];

    const int tid  = threadIdx.x;
    const int w    = tid >> 6;          // wave id 0..15
    const int lane = tid & 63;
    const int c0 = (w & 7) * 64;        // strip base col (8 strips cover 512)
    const int r0 = blockIdx.x * 64 + (w >> 3) * BROWS;   // 2 bands per block
    const size_t img_off = (size_t)blockIdx.y * (IMG * IMG);
    const float* __restrict__ xb = x + img_off;
    const float* __restrict__ yb = y + img_off;

    v4f (*wtile)[WUNITS] =
        reinterpret_cast<v4f (*)[WUNITS]>(dsm + (size_t)w * WAVE_LDS);

    // lane's output col = c0 + lane; taps at staged cols lane+3 .. lane+13
    // (stage base c0-8). Aligned 6 x b128 window starting at unit ub.
    const int ub = (lane + 3) >> 1;
    const int p  = (lane + 3) & 1;      // parity: tap k sits at window pos p+k

    // 12-tap per-lane weight vector: window pos m covers staged col 2*ub + m;
    // logical tap k = m - p, so wv2[m] = w[m-p] (0 outside [0,10]).
    v2f wv2[12];
    #pragma unroll
    for (int m = 0; m < 12; ++m) {
        float lo = (m <= 10) ? gw.w[m] : 0.f;       // p == 0
        float hi = (m >= 1) ? gw.w[m - 1] : 0.f;    // p == 1
        float wm = p ? hi : lo;
        wv2[m][0] = wm; wv2[m][1] = wm;
    }
    v2f wp[11];                          // vertical weights (parity-free)
    #pragma unroll
    for (int k = 0; k < 11; ++k) { wp[k][0] = gw.w[k]; wp[k][1] = gw.w[k]; }

    float4 sxr[4], syr[4];   // staged regs for next chunk (4 iters x 64 lanes >= 220)

    auto load_chunk = [&](int c) {
        #pragma unroll
        for (int it = 0; it < 4; ++it) {
            int idx = lane + it * 64;
            int row = idx / WQUADS;
            int q   = idx - row * WQUADS;
            int gr = r0 - 5 + c * CHR + row;       // global image row
            int gc = c0 - 8 + q * 4;               // global col of float4 (16B aligned)
            float4 vx = make_float4(0.f, 0.f, 0.f, 0.f);
            float4 vy = vx;
            if (idx < NQ && (unsigned)gr < IMG && (unsigned)gc < IMG) {
                const float* px = xb + (size_t)gr * IMG + gc;
                const float* py = yb + (size_t)gr * IMG + gc;
                vx = *(const float4*)px;
                vy = *(const float4*)py;
            }
            sxr[it] = vx; syr[it] = vy;
        }
    };
    // stage as u=x+y, v=x-y (unscaled; zero padding maps to zero: linear).
    // SINGLE buffer: these ds_writes are issued AFTER all ds_reads of the
    // current chunk (program order; DS pipe is in-order per wave), so the
    // overwrite cannot pass the reads. No barrier, no dbuf. (Proven R29.)
    auto store_chunk = [&]() {
        #pragma unroll
        for (int it = 0; it < 4; ++it) {
            int idx = lane + it * 64;
            if (idx < NQ) {
                int row = idx / WQUADS;
                int q   = idx - row * WQUADS;
                const float4 vx = sxr[it], vy = syr[it];
                wtile[row][q * 2]     = (v4f){vx.x + vy.x, vx.x - vy.x,
                                              vx.y + vy.y, vx.y - vy.y};
                wtile[row][q * 2 + 1] = (v4f){vx.z + vy.z, vx.z - vy.z,
                                              vx.w + vy.w, vx.w - vy.w};
            }
        }
    };

    v2f histL[11];     // (hu, hv)     -- linear channel H-conv results
    v2f histQ[11];     // (huu, hvv)   -- quadratic channel H-conv results
    float lsum = 0.f;
    const float C1x2 = 2e-4f, C2x2 = 1.8e-3f;   // 2*C1, 2*C2 (unscaled algebra)

    load_chunk(0);
    store_chunk();
    // no barrier: per-wave DS ordering + compiler lgkmcnt is the only sync.

    #pragma unroll 1
    for (int c = 0; c < NCHUNK; ++c) {      // 4 chunks x 11 rows = 44 >= 42
        if (c < NCHUNK - 1) load_chunk(c + 1);  // global loads overlap chunk-c compute

        #pragma unroll
        for (int s = 0; s < CHR; ++s) {     // H-row m = 11c + s; hist slot = s
            if (!(c == NCHUNK - 1 && s >= NHROW - (NCHUNK - 1) * CHR)) {   // m < 42
                v4f w6[6];
                #pragma unroll
                for (int i = 0; i < 6; ++i) w6[i] = wtile[s][ub + i];

                // --- horizontal conv: 12 taps, 3 packed ops each ---
                v2f hL = (v2f){0.f, 0.f};
                v2f hQ = (v2f){0.f, 0.f};
                #pragma unroll
                for (int m = 0; m < 12; ++m) {
                    v2f t = (m & 1) ? w6[m >> 1].zw : w6[m >> 1].xy;
                    hL = __builtin_elementwise_fma(wv2[m], t, hL);   // v_pk_fma_f32
                    v2f q = t * t;                                   // v_pk_mul_f32
                    hQ = __builtin_elementwise_fma(wv2[m], q, hQ);   // v_pk_fma_f32
                }
                histL[s] = hL; histQ[s] = hQ;

                // --- output row (11c + s - 10) completes now ---
                if (c > 0 || s == 10) {
                    v2f aL = (v2f){0.f, 0.f};
                    v2f aQ = (v2f){0.f, 0.f};
                    #pragma unroll
                    for (int j = 0; j < 11; ++j) {
                        const int sl = (s + 1 + j) % 11;   // static per (s,j)
                        aL = __builtin_elementwise_fma(wp[j], histL[sl], aL);
                        aQ = __builtin_elementwise_fma(wp[j], histQ[sl], aQ);
                    }
                    float a = aL[0] * aL[0], bq = aL[1] * aL[1];
                    float dm = a - bq;             // = 4 mx my
                    float sm = a + bq;             // = 2(mx^2 + my^2)
                    float num = (dm + C1x2) * ((aQ[0] - aQ[1]) - dm + C2x2);
                    float den = (sm + C1x2) * ((aQ[0] + aQ[1]) - sm + C2x2);
                    lsum += num * __builtin_amdgcn_rcpf(den);
                }
            }
        }

        // overwrite this wave's tile with the next chunk (in-order DS: safe)
        if (c < NCHUNK - 1) store_chunk();
    }

    // ---- reduction: wave shuffle -> LDS -> block partial -> fp64 atomic ----
    #pragma unroll
    for (int off = 32; off > 0; off >>= 1)
        lsum += __shfl_down(lsum, off, 64);
    if (lane == 0) wavesum[w] = lsum;
    __syncthreads();
    if (tid == 0) {
        float bs = 0.f;
        #pragma unroll
        for (int i = 0; i < 16; ++i) bs += wavesum[i];
        atomicAdd(acc_ws, (double)bs);
        __threadfence();
        unsigned long long old = atomicAdd(ctr, 1ull);
        if (old == (unsigned long long)(NBLOCKS - 1)) {
            __threadfence();
            double total = atomicAdd(acc_ws, 0.0);   // atomic RMW sees all prior adds
            out[0] = (float)(1.0 - total / NPIX);
        }
    }
}

extern "C" void kernel_launch(void* const* d_in, const int* in_sizes, int n_in,
                              void* d_out, int out_size, void* d_ws, size_t ws_size,
                              hipStream_t stream) {
    const float* x = (const float*)d_in[0];   // heatmap_clean
    const float* y = (const float*)d_in[1];   // heatmap_adv
    float* out = (float*)d_out;
    double* acc = (double*)d_ws;
    unsigned long long* ctr = (unsigned long long*)((char*)d_ws + 8);

    // allow > 64 KB dynamic LDS (host-side attribute, graph-capture safe)
    static bool attr_set = false;
    if (!attr_set) {
        hipFuncSetAttribute(reinterpret_cast<const void*>(ssim_stream_kernel),
                            hipFuncAttributeMaxDynamicSharedMemorySize, LDS_BYTES);
        attr_set = true;
    }

    // zero the 16B of accumulator+counter state (capture-safe async memset)
    hipMemsetAsync(d_ws, 0, 16, stream);

    GaussW gw;
    double g[11], s = 0.0;
    for (int i = 0; i < 11; ++i) { double d = i - 5; g[i] = exp(-(d * d) / 4.5); s += g[i]; }
    for (int i = 0; i < 11; ++i) gw.w[i] = (float)(g[i] / s);

    dim3 grid(IMG / 64, 32);   // (8, 32) = 256 blocks = 1/CU, 16 indep waves forced
    ssim_stream_kernel<<<grid, 1024, LDS_BYTES, stream>>>(x, y, acc, ctr, out, gw);
}

// Round 16
// 119.742 us; speedup vs baseline: 1.2983x; 1.2983x over previous
//
#include <hip/hip_runtime.h>
#include <cmath>

// SSIM stability loss: 1 - mean(SSIM(x,y)), 11x11 Gaussian (sigma=1.5), zero SAME
// padding, fp32, 32 x 1 x 512 x 512.
//
// R32 = R26 exact restoration (proven best: 42.0 us). R31's experiment was
// invalidated at its tripwire: hipcc hard-caps 1024-thr workgroups at 64
// VGPR even with launch_bounds(1024,1) -> 90MB scratch spill (2nd
// confirmation after R24). Established bounds: >512-thr blocks unusable
// (compiler); multi-block co-residency never materializes (R16/R29, occ
// pinned ~15-17% at 2 fitting blocks/CU). So 2 waves/SIMD is the reachable
// max, and R26 is the best config there. Exploration complete across TLP,
// barriers, ILP, MLP, wait density, chain depth, LDS volume, work volume.
// Plateau decomposition: VALU ~18us + LDS ~12-18us, serializing at
// 2 waves/SIMD. This round: reproduce 42us to validate the plateau value.
//
// Structure: one 512-thr block/CU (grid (8,32)=256); 8 barrier-free
// independent waves, each owning a 64-col strip x 64-row band with a
// private double-buffered 11-row LDS tile (16 x 7040 B dynamic); in-order
// per-wave DS is the only sync. Inner loop: unscaled sum/diff channels
// u=x+y, v=x-y + squares (2C1/2C2 algebra); 6 aligned ds_read_b128/row;
// parity-folded 12-tap weight vector; 11-deep circular history; fp64
// atomic finish.
// Predict: dur 42.0+-1, VGPR 80, WRITE ~16B, occ ~16%, VALUBusy ~43%.

#define IMG   512
#define BROWS 64
#define NHROW (BROWS + 10)   // 74 H-rows per band
#define NCHUNK 7             // ceil(74/11)
#define CHR   11             // rows per LDS chunk (== history depth)
#define WQUADS 20            // float4 col-quads staged per row per wave (80 cols)
#define WUNITS 40            // v4f units per staged row per wave
#define NQ (CHR * WQUADS)    // 220 quads per chunk per wave
#define WAVE_LDS (2 * CHR * WUNITS)        // v4f units per wave (dbuf)
#define LDS_BYTES (8 * WAVE_LDS * 16)      // 112640
#define NBLOCKS 256
#define NPIX  8388608.0

typedef float v2f __attribute__((ext_vector_type(2)));
typedef float v4f __attribute__((ext_vector_type(4)));

struct GaussW { float w[11]; };

__global__ __launch_bounds__(512, 1)
void ssim_stream_kernel(const float* __restrict__ x, const float* __restrict__ y,
                        double* __restrict__ acc_ws, unsigned long long* __restrict__ ctr,
                        float* __restrict__ out, GaussW gw) {
    extern __shared__ v4f dsm[];        // [8 waves][2 bufs][CHR][WUNITS]
    __shared__ float wavesum[8];

    const int tid  = threadIdx.x;
    const int w    = tid >> 6;          // wave id 0..7, owns a 64-col strip
    const int lane = tid & 63;
    const int c0 = w * 64;              // strip base col (block covers all 512)
    const int r0 = blockIdx.x * BROWS;
    const size_t img_off = (size_t)blockIdx.y * (IMG * IMG);
    const float* __restrict__ xb = x + img_off;
    const float* __restrict__ yb = y + img_off;

    v4f (*wtile)[CHR][WUNITS] =
        reinterpret_cast<v4f (*)[CHR][WUNITS]>(dsm + (size_t)w * WAVE_LDS);

    // lane's output col = c0 + lane; taps at staged cols lane+3 .. lane+13
    // (stage base c0-8). Aligned 6 x b128 window starting at unit ub.
    const int ub = (lane + 3) >> 1;
    const int p  = (lane + 3) & 1;      // parity: tap k sits at window pos p+k

    // 12-tap per-lane weight vector: window pos m covers staged col 2*ub + m;
    // logical tap k = m - p, so wv2[m] = w[m-p] (0 outside [0,10]).
    v2f wv2[12];
    #pragma unroll
    for (int m = 0; m < 12; ++m) {
        float lo = (m <= 10) ? gw.w[m] : 0.f;       // p == 0
        float hi = (m >= 1) ? gw.w[m - 1] : 0.f;    // p == 1
        float wm = p ? hi : lo;
        wv2[m][0] = wm; wv2[m][1] = wm;
    }
    v2f wp[11];                          // vertical weights (parity-free)
    #pragma unroll
    for (int k = 0; k < 11; ++k) { wp[k][0] = gw.w[k]; wp[k][1] = gw.w[k]; }

    float4 sxr[4], syr[4];   // staged regs for next chunk (4 iters x 64 lanes >= 220)

    auto load_chunk = [&](int c) {
        #pragma unroll
        for (int it = 0; it < 4; ++it) {
            int idx = lane + it * 64;
            int row = idx / WQUADS;
            int q   = idx - row * WQUADS;
            int gr = r0 - 5 + c * CHR + row;       // global image row
            int gc = c0 - 8 + q * 4;               // global col of float4 (16B aligned)
            float4 vx = make_float4(0.f, 0.f, 0.f, 0.f);
            float4 vy = vx;
            if (idx < NQ && (unsigned)gr < IMG && (unsigned)gc < IMG) {
                const float* px = xb + (size_t)gr * IMG + gc;
                const float* py = yb + (size_t)gr * IMG + gc;
                vx = *(const float4*)px;
                vy = *(const float4*)py;
            }
            sxr[it] = vx; syr[it] = vy;
        }
    };
    // stage as u=x+y, v=x-y (unscaled; zero padding maps to zero: linear)
    auto store_chunk = [&](int b) {
        #pragma unroll
        for (int it = 0; it < 4; ++it) {
            int idx = lane + it * 64;
            if (idx < NQ) {
                int row = idx / WQUADS;
                int q   = idx - row * WQUADS;
                const float4 vx = sxr[it], vy = syr[it];
                wtile[b][row][q * 2]     = (v4f){vx.x + vy.x, vx.x - vy.x,
                                                 vx.y + vy.y, vx.y - vy.y};
                wtile[b][row][q * 2 + 1] = (v4f){vx.z + vy.z, vx.z - vy.z,
                                                 vx.w + vy.w, vx.w - vy.w};
            }
        }
    };

    v2f histL[11];     // (hu, hv)     -- linear channel H-conv results
    v2f histQ[11];     // (huu, hvv)   -- quadratic channel H-conv results
    float lsum = 0.f;
    const float C1x2 = 2e-4f, C2x2 = 1.8e-3f;   // 2*C1, 2*C2 (unscaled algebra)

    load_chunk(0);
    store_chunk(0);
    // no barrier: DS ops of one wave complete in order; compiler inserts the
    // lgkmcnt before the first dependent ds_read use.

    #pragma unroll 1
    for (int c = 0; c < NCHUNK; ++c) {      // 7 chunks x 11 rows = 77 >= 74
        const int b = c & 1;
        if (c < NCHUNK - 1) load_chunk(c + 1);  // global loads overlap chunk-c compute

        #pragma unroll
        for (int s = 0; s < CHR; ++s) {     // H-row m = 11c + s; hist slot = s
            if (!(c == NCHUNK - 1 && s >= NHROW - (NCHUNK - 1) * CHR)) {   // m < 74
                v4f w6[6];
                #pragma unroll
                for (int i = 0; i < 6; ++i) w6[i] = wtile[b][s][ub + i];

                // --- horizontal conv: 12 taps, 3 packed ops each ---
                v2f hL = (v2f){0.f, 0.f};
                v2f hQ = (v2f){0.f, 0.f};
                #pragma unroll
                for (int m = 0; m < 12; ++m) {
                    v2f t = (m & 1) ? w6[m >> 1].zw : w6[m >> 1].xy;
                    hL = __builtin_elementwise_fma(wv2[m], t, hL);   // v_pk_fma_f32
                    v2f q = t * t;                                   // v_pk_mul_f32
                    hQ = __builtin_elementwise_fma(wv2[m], q, hQ);   // v_pk_fma_f32
                }
                histL[s] = hL; histQ[s] = hQ;

                // --- output row (11c + s - 10) completes now ---
                if (c > 0 || s == 10) {
                    v2f aL = (v2f){0.f, 0.f};
                    v2f aQ = (v2f){0.f, 0.f};
                    #pragma unroll
                    for (int j = 0; j < 11; ++j) {
                        const int sl = (s + 1 + j) % 11;   // static per (s,j)
                        aL = __builtin_elementwise_fma(wp[j], histL[sl], aL);
                        aQ = __builtin_elementwise_fma(wp[j], histQ[sl], aQ);
                    }
                    float a = aL[0] * aL[0], bq = aL[1] * aL[1];
                    float dm = a - bq;             // = 4 mx my
                    float sm = a + bq;             // = 2(mx^2 + my^2)
                    float num = (dm + C1x2) * ((aQ[0] - aQ[1]) - dm + C2x2);
                    float den = (sm + C1x2) * ((aQ[0] + aQ[1]) - sm + C2x2);
                    lsum += num * __builtin_amdgcn_rcpf(den);
                }
            }
        }

        // write next chunk into this wave's OTHER buffer -- no barrier needed,
        // reads of buffer b above are older DS ops of the same wave (in-order).
        if (c < NCHUNK - 1) store_chunk(b ^ 1);
    }

    // ---- reduction: wave shuffle -> LDS -> block partial -> fp64 atomic ----
    #pragma unroll
    for (int off = 32; off > 0; off >>= 1)
        lsum += __shfl_down(lsum, off, 64);
    if (lane == 0) wavesum[w] = lsum;
    __syncthreads();
    if (tid == 0) {
        float bs = 0.f;
        #pragma unroll
        for (int i = 0; i < 8; ++i) bs += wavesum[i];
        atomicAdd(acc_ws, (double)bs);
        __threadfence();
        unsigned long long old = atomicAdd(ctr, 1ull);
        if (old == (unsigned long long)(NBLOCKS - 1)) {
            __threadfence();
            double total = atomicAdd(acc_ws, 0.0);   // atomic RMW sees all prior adds
            out[0] = (float)(1.0 - total / NPIX);
        }
    }
}

extern "C" void kernel_launch(void* const* d_in, const int* in_sizes, int n_in,
                              void* d_out, int out_size, void* d_ws, size_t ws_size,
                              hipStream_t stream) {
    const float* x = (const float*)d_in[0];   // heatmap_clean
    const float* y = (const float*)d_in[1];   // heatmap_adv
    float* out = (float*)d_out;
    double* acc = (double*)d_ws;
    unsigned long long* ctr = (unsigned long long*)((char*)d_ws + 8);

    // allow > 64 KB dynamic LDS (host-side attribute, graph-capture safe)
    static bool attr_set = false;
    if (!attr_set) {
        hipFuncSetAttribute(reinterpret_cast<const void*>(ssim_stream_kernel),
                            hipFuncAttributeMaxDynamicSharedMemorySize, LDS_BYTES);
        attr_set = true;
    }

    // zero the 16B of accumulator+counter state (capture-safe async memset)
    hipMemsetAsync(d_ws, 0, 16, stream);

    GaussW gw;
    double g[11], s = 0.0;
    for (int i = 0; i < 11; ++i) { double d = i - 5; g[i] = exp(-(d * d) / 4.5); s += g[i]; }
    for (int i = 0; i < 11; ++i) gw.w[i] = (float)(g[i] / s);

    dim3 grid(IMG / BROWS, 32);   // (8, 32) = 256 blocks = 1/CU, 8 indep waves forced
    ssim_stream_kernel<<<grid, 512, LDS_BYTES, stream>>>(x, y, acc, ctr, out, gw);
}

// Round 17
// 117.473 us; speedup vs baseline: 1.3234x; 1.0193x over previous
//
#include <hip/hip_runtime.h>
#include <cmath>

// SSIM stability loss: 1 - mean(SSIM(x,y)), 11x11 Gaussian (sigma=1.5), zero SAME
// padding, fp32, 32 x 1 x 512 x 512.
//
// R33: hedged final TLP experiment. R32 proved byte-identical code measures
// 42 vs 58-62us across sessions (clock/env noise; harness delta only +4us) --
// R26 remains the best config. The only unclosed axis: VALID forced 16-wave
// residency. R24/R31 both died to hipcc's 64-VGPR budget for 1024-thr
// workgroups (a default occupancy-target heuristic, not a HW limit: 4
// waves/SIMD allows 128). Untried documented knob: amdgpu_waves_per_eu(4,4)
// -> allocator targets exactly 4 waves/EU -> VGPR cap 128, natural ~80.
// HEDGE: compile both ssim16 (16-wave, attr) and ssim8 (R26 exact); at
// launch, hipFuncGetAttributes(ssim16).localSizeBytes == 0 (no spill) picks
// ssim16, else ssim8. Downside = R26 exactly; upside = first valid 16-wave.
//
// Shared inner loop (verified R26/R31): barrier-free per-wave private LDS
// tiles, in-order per-wave DS as only sync; unscaled sum/diff channels
// u=x+y, v=x-y + squares (2C1/2C2 algebra); 6 aligned ds_read_b128/row;
// parity-folded 12-tap weight vector; 11-deep circular history; fp64
// atomic finish.
//
// Predict: attr honored -> WG=1024, VGPR 80-128, WRITE ~16B, occ 35-50%,
// dur 28-35us (TLP pays) or 42-48 (structural plateau, declare next).
// attr ignored -> WG=512, R26 repro ~42us clean-env.

#define IMG   512
#define CHR   11             // rows per LDS chunk (== history depth)
#define WQUADS 20            // float4 col-quads staged per row per wave (80 cols)
#define WUNITS 40            // v4f units per staged row per wave
#define NQ (CHR * WQUADS)    // 220 quads per chunk per wave
#define LDS_BYTES 112640     // 8 waves x dbuf x 7040  ==  16 waves x 7040
#define NBLOCKS 256
#define NPIX  8388608.0

typedef float v2f __attribute__((ext_vector_type(2)));
typedef float v4f __attribute__((ext_vector_type(4)));

struct GaussW { float w[11]; };

// Per-wave streaming worker. tile0 points at this wave's tile (DBUF: two
// consecutive CHR*WUNITS buffers). Verified-equivalent to R26 (DBUF=1,
// NCHUNKT=7, NHROWT=74) and R31 (DBUF=0, NCHUNKT=4, NHROWT=42) bodies.
template<int NCHUNKT, int NHROWT, bool DBUF>
__device__ __forceinline__
float wave_stream(const float* __restrict__ xb, const float* __restrict__ yb,
                  v4f* __restrict__ tile0, int c0, int r0, int lane,
                  const GaussW& gw) {
    // lane's output col = c0 + lane; taps at staged cols lane+3 .. lane+13
    // (stage base c0-8). Aligned 6 x b128 window starting at unit ub.
    const int ub = (lane + 3) >> 1;
    const int p  = (lane + 3) & 1;      // parity: tap k sits at window pos p+k

    // 12-tap per-lane weight vector: window pos m covers staged col 2*ub + m;
    // logical tap k = m - p, so wv2[m] = w[m-p] (0 outside [0,10]).
    v2f wv2[12];
    #pragma unroll
    for (int m = 0; m < 12; ++m) {
        float lo = (m <= 10) ? gw.w[m] : 0.f;       // p == 0
        float hi = (m >= 1) ? gw.w[m - 1] : 0.f;    // p == 1
        float wm = p ? hi : lo;
        wv2[m][0] = wm; wv2[m][1] = wm;
    }
    v2f wp[11];                          // vertical weights (parity-free)
    #pragma unroll
    for (int k = 0; k < 11; ++k) { wp[k][0] = gw.w[k]; wp[k][1] = gw.w[k]; }

    float4 sxr[4], syr[4];   // staged regs for next chunk (4 iters x 64 lanes >= 220)

    auto load_chunk = [&](int c) {
        #pragma unroll
        for (int it = 0; it < 4; ++it) {
            int idx = lane + it * 64;
            int row = idx / WQUADS;
            int q   = idx - row * WQUADS;
            int gr = r0 - 5 + c * CHR + row;       // global image row
            int gc = c0 - 8 + q * 4;               // global col of float4 (16B aligned)
            float4 vx = make_float4(0.f, 0.f, 0.f, 0.f);
            float4 vy = vx;
            if (idx < NQ && (unsigned)gr < IMG && (unsigned)gc < IMG) {
                const float* px = xb + (size_t)gr * IMG + gc;
                const float* py = yb + (size_t)gr * IMG + gc;
                vx = *(const float4*)px;
                vy = *(const float4*)py;
            }
            sxr[it] = vx; syr[it] = vy;
        }
    };
    // stage as u=x+y, v=x-y (unscaled; zero padding maps to zero: linear).
    // Writes are issued after all reads of the buffer being overwritten
    // (program order; per-wave DS is in-order) -> no barrier needed.
    auto store_chunk = [&](int b) {
        v4f* t = tile0 + (DBUF ? b * (CHR * WUNITS) : 0);
        #pragma unroll
        for (int it = 0; it < 4; ++it) {
            int idx = lane + it * 64;
            if (idx < NQ) {
                int row = idx / WQUADS;
                int q   = idx - row * WQUADS;
                const float4 vx = sxr[it], vy = syr[it];
                t[row * WUNITS + q * 2]     = (v4f){vx.x + vy.x, vx.x - vy.x,
                                                    vx.y + vy.y, vx.y - vy.y};
                t[row * WUNITS + q * 2 + 1] = (v4f){vx.z + vy.z, vx.z - vy.z,
                                                    vx.w + vy.w, vx.w - vy.w};
            }
        }
    };

    v2f histL[11];     // (hu, hv)     -- linear channel H-conv results
    v2f histQ[11];     // (huu, hvv)   -- quadratic channel H-conv results
    float lsum = 0.f;
    const float C1x2 = 2e-4f, C2x2 = 1.8e-3f;   // 2*C1, 2*C2 (unscaled algebra)

    load_chunk(0);
    store_chunk(0);
    // no barrier: per-wave DS ordering + compiler lgkmcnt is the only sync.

    #pragma unroll 1
    for (int c = 0; c < NCHUNKT; ++c) {
        const int b = DBUF ? (c & 1) : 0;
        v4f* tb = tile0 + (DBUF ? b * (CHR * WUNITS) : 0);
        if (c < NCHUNKT - 1) load_chunk(c + 1);  // global loads overlap compute

        #pragma unroll
        for (int s = 0; s < CHR; ++s) {     // H-row m = CHR*c + s; hist slot = s
            if (!(c == NCHUNKT - 1 && s >= NHROWT - (NCHUNKT - 1) * CHR)) {
                v4f w6[6];
                #pragma unroll
                for (int i = 0; i < 6; ++i) w6[i] = tb[s * WUNITS + ub + i];

                // --- horizontal conv: 12 taps, 3 packed ops each ---
                v2f hL = (v2f){0.f, 0.f};
                v2f hQ = (v2f){0.f, 0.f};
                #pragma unroll
                for (int m = 0; m < 12; ++m) {
                    v2f t = (m & 1) ? w6[m >> 1].zw : w6[m >> 1].xy;
                    hL = __builtin_elementwise_fma(wv2[m], t, hL);   // v_pk_fma_f32
                    v2f q = t * t;                                   // v_pk_mul_f32
                    hQ = __builtin_elementwise_fma(wv2[m], q, hQ);   // v_pk_fma_f32
                }
                histL[s] = hL; histQ[s] = hQ;

                // --- output row (CHR*c + s - 10) completes now ---
                if (c > 0 || s == 10) {
                    v2f aL = (v2f){0.f, 0.f};
                    v2f aQ = (v2f){0.f, 0.f};
                    #pragma unroll
                    for (int j = 0; j < 11; ++j) {
                        const int sl = (s + 1 + j) % 11;   // static per (s,j)
                        aL = __builtin_elementwise_fma(wp[j], histL[sl], aL);
                        aQ = __builtin_elementwise_fma(wp[j], histQ[sl], aQ);
                    }
                    float a = aL[0] * aL[0], bq = aL[1] * aL[1];
                    float dm = a - bq;             // = 4 mx my
                    float sm = a + bq;             // = 2(mx^2 + my^2)
                    float num = (dm + C1x2) * ((aQ[0] - aQ[1]) - dm + C2x2);
                    float den = (sm + C1x2) * ((aQ[0] + aQ[1]) - sm + C2x2);
                    lsum += num * __builtin_amdgcn_rcpf(den);
                }
            }
        }

        if (c < NCHUNKT - 1) store_chunk(DBUF ? (b ^ 1) : 0);
    }
    return lsum;
}

__device__ __forceinline__
void finish(float lsum, float* wavesum, int nw, int tid, int lane, int w,
            double* acc_ws, unsigned long long* ctr, float* out) {
    #pragma unroll
    for (int off = 32; off > 0; off >>= 1)
        lsum += __shfl_down(lsum, off, 64);
    if (lane == 0) wavesum[w] = lsum;
    __syncthreads();
    if (tid == 0) {
        float bs = 0.f;
        for (int i = 0; i < nw; ++i) bs += wavesum[i];
        atomicAdd(acc_ws, (double)bs);
        __threadfence();
        unsigned long long old = atomicAdd(ctr, 1ull);
        if (old == (unsigned long long)(NBLOCKS - 1)) {
            __threadfence();
            double total = atomicAdd(acc_ws, 0.0);   // atomic RMW sees all prior adds
            out[0] = (float)(1.0 - total / NPIX);
        }
    }
}

// ---- ssim8: R26 exact structure (proven best, 42us): 8 dbuf waves, 64-row band
__global__ __launch_bounds__(512, 1)
void ssim8(const float* __restrict__ x, const float* __restrict__ y,
           double* __restrict__ acc_ws, unsigned long long* __restrict__ ctr,
           float* __restrict__ out, GaussW gw) {
    extern __shared__ v4f dsm[];        // [8 waves][2 bufs][CHR][WUNITS]
    __shared__ float wavesum[8];
    const int tid  = threadIdx.x;
    const int w    = tid >> 6;
    const int lane = tid & 63;
    const size_t img_off = (size_t)blockIdx.y * (IMG * IMG);
    float lsum = wave_stream<7, 74, true>(
        x + img_off, y + img_off, dsm + (size_t)w * (2 * CHR * WUNITS),
        w * 64, blockIdx.x * 64, lane, gw);
    finish(lsum, wavesum, 8, tid, lane, w, acc_ws, ctr, out);
}

// ---- ssim16: R31 structure (16 single-buffer waves, 32-row bands) with the
// allocator knob: waves_per_eu(4,4) -> VGPR budget 128 (not the 64 default).
__global__ __launch_bounds__(1024)
__attribute__((amdgpu_waves_per_eu(4, 4)))
void ssim16(const float* __restrict__ x, const float* __restrict__ y,
            double* __restrict__ acc_ws, unsigned long long* __restrict__ ctr,
            float* __restrict__ out, GaussW gw) {
    extern __shared__ v4f dsm[];        // [16 waves][CHR][WUNITS]
    __shared__ float wavesum[16];
    const int tid  = threadIdx.x;
    const int w    = tid >> 6;          // 0..15
    const int lane = tid & 63;
    const size_t img_off = (size_t)blockIdx.y * (IMG * IMG);
    float lsum = wave_stream<4, 42, false>(
        x + img_off, y + img_off, dsm + (size_t)w * (CHR * WUNITS),
        (w & 7) * 64, blockIdx.x * 64 + (w >> 3) * 32, lane, gw);
    finish(lsum, wavesum, 16, tid, lane, w, acc_ws, ctr, out);
}

extern "C" void kernel_launch(void* const* d_in, const int* in_sizes, int n_in,
                              void* d_out, int out_size, void* d_ws, size_t ws_size,
                              hipStream_t stream) {
    const float* x = (const float*)d_in[0];   // heatmap_clean
    const float* y = (const float*)d_in[1];   // heatmap_adv
    float* out = (float*)d_out;
    double* acc = (double*)d_ws;
    unsigned long long* ctr = (unsigned long long*)((char*)d_ws + 8);

    // One-time host-side setup: allow >64KB dynamic LDS on both kernels and
    // pick ssim16 only if it compiled spill-free (localSizeBytes == 0).
    // hipFuncGetAttributes/SetAttribute are module queries, capture-safe.
    static int use16 = -1;
    if (use16 < 0) {
        hipFuncSetAttribute(reinterpret_cast<const void*>(ssim8),
                            hipFuncAttributeMaxDynamicSharedMemorySize, LDS_BYTES);
        hipFuncSetAttribute(reinterpret_cast<const void*>(ssim16),
                            hipFuncAttributeMaxDynamicSharedMemorySize, LDS_BYTES);
        hipFuncAttributes fa{};
        use16 = 0;
        if (hipFuncGetAttributes(&fa, reinterpret_cast<const void*>(ssim16)) == hipSuccess)
            use16 = (fa.localSizeBytes == 0) ? 1 : 0;   // spill-free -> valid experiment
    }

    // zero the 16B of accumulator+counter state (capture-safe async memset)
    hipMemsetAsync(d_ws, 0, 16, stream);

    GaussW gw;
    double g[11], s = 0.0;
    for (int i = 0; i < 11; ++i) { double d = i - 5; g[i] = exp(-(d * d) / 4.5); s += g[i]; }
    for (int i = 0; i < 11; ++i) gw.w[i] = (float)(g[i] / s);

    dim3 grid(IMG / 64, 32);   // (8, 32) = 256 blocks = 1 per CU (both kernels)
    if (use16)
        ssim16<<<grid, 1024, LDS_BYTES, stream>>>(x, y, acc, ctr, out, gw);
    else
        ssim8<<<grid, 512, LDS_BYTES, stream>>>(x, y, acc, ctr, out, gw);
}

// Round 18
// 117.404 us; speedup vs baseline: 1.3242x; 1.0006x over previous
//
#include <hip/hip_runtime.h>
#include <cmath>

// SSIM stability loss: 1 - mean(SSIM(x,y)), 11x11 Gaussian (sigma=1.5), zero SAME
// padding, fp32, 32 x 1 x 512 x 512.
//
// R34: 2-col/thread in the barrier-free forced-resident structure (untested
// cell). R33 validly closed the TLP axis (waves_per_eu(4,4) also spills at
// 1024 thr; hedge correctly fell back to ssim8, 43.4-44.6us = R26 repro).
// R21's "2-col = neutral" was measured in the barrier-coupled block-tile
// structure where the convoy set the pace; in the wave-private structure
// time tracks per-wave work (R19: -20% work -> -20% time). 2-col cuts BOTH
// pipes: 7 ds_read_b128 per 2 cols (-34% LDS reads/output) and shared
// squares + fixed parity (56 H-ops/row-pair; with 42/32 halo -6.6% VALU/
// output; padded wv2[12] eliminated -> wp[11] shared by H and V).
//
// Geometry: wave = 128 out cols x 32-row band; strip (w&3)*128, band
// r0 = bx*64 + (w>>2)*32; 8 waves/512-thr block; grid (8,32)=256 = 1/CU;
// single-buffer private tile 11 x 72 v4f = 12.7KB/wave -> 101.4KB dynamic.
// In-order per-wave DS is the only sync (proven R26/R29/R31).
// VGPR risk: history doubles (88 fl); naive ~200, R20 precedent ~2/3 ->
// ~140-180; (512,1) allows up to 256 at 2 waves/SIMD. HEDGE: ssim8 (R26)
// compiled alongside; 2-col selected only if localSizeBytes == 0.
//
// Predict (2-col selected): VGPR 140-200, WRITE ~16B, dur 36-40us
// (VALU-scaling) or 33-37 (LDS relief), FETCH 39-45MB. Spill -> ssim8
// ~43-45. PRE-COMMIT: <5% gain -> declare structural plateau next round.

#define IMG   512
#define CHR   11             // rows per LDS chunk (== history depth)
#define NPIX  8388608.0
#define NBLOCKS 256

// ---- 1-col (ssim8 / R26) geometry
#define WQUADS 20            // float4 col-quads staged per row per wave (80 cols)
#define WUNITS 40            // v4f units per staged row per wave
#define NQ1 (CHR * WQUADS)   // 220
#define LDS8_BYTES (8 * 2 * CHR * WUNITS * 16)   // 112640

// ---- 2-col geometry
#define SQUADS 36            // float4 quads per staged row (144 cols)
#define SUNITS 72            // v4f units per staged row
#define NQ2 (CHR * SQUADS)   // 396
#define WAVE2_LDS (CHR * SUNITS)                 // 792 v4f units = 12672 B
#define LDS2_BYTES (8 * WAVE2_LDS * 16)          // 101376

typedef float v2f __attribute__((ext_vector_type(2)));
typedef float v4f __attribute__((ext_vector_type(4)));

struct GaussW { float w[11]; };

__device__ __forceinline__
void finish(float lsum, float* wavesum, int nw, int tid, int lane, int w,
            double* acc_ws, unsigned long long* ctr, float* out) {
    #pragma unroll
    for (int off = 32; off > 0; off >>= 1)
        lsum += __shfl_down(lsum, off, 64);
    if (lane == 0) wavesum[w] = lsum;
    __syncthreads();
    if (tid == 0) {
        float bs = 0.f;
        for (int i = 0; i < nw; ++i) bs += wavesum[i];
        atomicAdd(acc_ws, (double)bs);
        __threadfence();
        unsigned long long old = atomicAdd(ctr, 1ull);
        if (old == (unsigned long long)(NBLOCKS - 1)) {
            __threadfence();
            double total = atomicAdd(acc_ws, 0.0);   // atomic RMW sees all prior adds
            out[0] = (float)(1.0 - total / NPIX);
        }
    }
}

// =====================  ssim2c: 2 cols/thread, 8 waves  =====================
__global__ __launch_bounds__(512, 1)
void ssim2c(const float* __restrict__ x, const float* __restrict__ y,
            double* __restrict__ acc_ws, unsigned long long* __restrict__ ctr,
            float* __restrict__ out, GaussW gw) {
    extern __shared__ v4f dsm[];        // [8 waves][CHR][SUNITS]
    __shared__ float wavesum[8];

    const int tid  = threadIdx.x;
    const int w    = tid >> 6;          // wave id 0..7
    const int lane = tid & 63;
    const int c0 = (w & 3) * 128;       // strip base col (4 strips x 128 = 512)
    const int r0 = blockIdx.x * 64 + (w >> 2) * 32;   // 2 sub-bands of 32 rows
    const size_t img_off = (size_t)blockIdx.y * (IMG * IMG);
    const float* __restrict__ xb = x + img_off;
    const float* __restrict__ yb = y + img_off;

    v4f* tile = dsm + (size_t)w * WAVE2_LDS;

    // lane's output cols = c0+2*lane, c0+2*lane+1. Tap union spans staged
    // cols 2l+3 .. 2l+14 (stage base c0-8) = units l+1 .. l+7 (7 x b128).
    // Window pos m (staged col 2l+2+m): colA taps m=1..11 (k=m-1), colB
    // m=2..12 (k=m-2). FIXED parity for all lanes -> wp[] only.
    const int ub = lane + 1;

    v2f wp[11];                          // weights, shared by H and V conv
    #pragma unroll
    for (int k = 0; k < 11; ++k) { wp[k][0] = gw.w[k]; wp[k][1] = gw.w[k]; }

    float4 sxr[7], syr[7];   // staged regs (7 iters x 64 lanes >= 396)

    auto load_chunk = [&](int c) {
        #pragma unroll
        for (int it = 0; it < 7; ++it) {
            int idx = lane + it * 64;
            int row = idx / SQUADS;
            int q   = idx - row * SQUADS;
            int gr = r0 - 5 + c * CHR + row;       // global image row
            int gc = c0 - 8 + q * 4;               // global col of float4 (16B aligned)
            float4 vx = make_float4(0.f, 0.f, 0.f, 0.f);
            float4 vy = vx;
            if (idx < NQ2 && (unsigned)gr < IMG && (unsigned)gc < IMG) {
                const float* px = xb + (size_t)gr * IMG + gc;
                const float* py = yb + (size_t)gr * IMG + gc;
                vx = *(const float4*)px;
                vy = *(const float4*)py;
            }
            sxr[it] = vx; syr[it] = vy;
        }
    };
    // stage as u=x+y, v=x-y. SINGLE buffer: writes are issued after all reads
    // of the chunk (program order; per-wave DS in-order) -> race-free.
    auto store_chunk = [&]() {
        #pragma unroll
        for (int it = 0; it < 7; ++it) {
            int idx = lane + it * 64;
            if (idx < NQ2) {
                int row = idx / SQUADS;
                int q   = idx - row * SQUADS;
                const float4 vx = sxr[it], vy = syr[it];
                tile[row * SUNITS + q * 2]     = (v4f){vx.x + vy.x, vx.x - vy.x,
                                                       vx.y + vy.y, vx.y - vy.y};
                tile[row * SUNITS + q * 2 + 1] = (v4f){vx.z + vy.z, vx.z - vy.z,
                                                       vx.w + vy.w, vx.w - vy.w};
            }
        }
    };

    v2f hLA[11], hQA[11];   // col A history: (hu,hv), (huu,hvv)
    v2f hLB[11], hQB[11];   // col B
    float lsum = 0.f;
    const float C1x2 = 2e-4f, C2x2 = 1.8e-3f;   // 2*C1, 2*C2 (unscaled algebra)

    auto vout = [&](const v2f (&hL)[11], const v2f (&hQ)[11], int s) {
        v2f aL = (v2f){0.f, 0.f};
        v2f aQ = (v2f){0.f, 0.f};
        #pragma unroll
        for (int j = 0; j < 11; ++j) {
            const int sl = (s + 1 + j) % 11;   // static per (s,j)
            aL = __builtin_elementwise_fma(wp[j], hL[sl], aL);
            aQ = __builtin_elementwise_fma(wp[j], hQ[sl], aQ);
        }
        float a = aL[0] * aL[0], bq = aL[1] * aL[1];
        float dm = a - bq;             // = 4 mx my
        float sm = a + bq;             // = 2(mx^2 + my^2)
        float num = (dm + C1x2) * ((aQ[0] - aQ[1]) - dm + C2x2);
        float den = (sm + C1x2) * ((aQ[0] + aQ[1]) - sm + C2x2);
        lsum += num * __builtin_amdgcn_rcpf(den);
    };

    load_chunk(0);
    store_chunk();
    // no barrier: per-wave DS ordering + compiler lgkmcnt is the only sync.

    #pragma unroll 1
    for (int c = 0; c < 4; ++c) {           // 4 chunks x 11 rows = 44 >= 42
        if (c < 3) load_chunk(c + 1);       // global loads overlap compute

        #pragma unroll
        for (int s = 0; s < CHR; ++s) {     // H-row m = 11c + s; hist slot = s
            if (!(c == 3 && s >= 9)) {      // m < 42
                v4f w7[7];
                #pragma unroll
                for (int i = 0; i < 7; ++i) w7[i] = tile[s * SUNITS + ub + i];

                // --- horizontal conv, both cols, shared squares ---
                v2f LA = (v2f){0.f, 0.f}, QA = (v2f){0.f, 0.f};
                v2f LB = (v2f){0.f, 0.f}, QB = (v2f){0.f, 0.f};
                #pragma unroll
                for (int m = 1; m <= 12; ++m) {      // staged col 2l+2+m
                    v2f t = (m & 1) ? w7[m >> 1].zw : w7[m >> 1].xy;
                    v2f q = t * t;                                   // shared square
                    if (m <= 11) {   // col A tap k = m-1
                        LA = __builtin_elementwise_fma(wp[m - 1], t, LA);
                        QA = __builtin_elementwise_fma(wp[m - 1], q, QA);
                    }
                    if (m >= 2) {    // col B tap k = m-2
                        LB = __builtin_elementwise_fma(wp[m - 2], t, LB);
                        QB = __builtin_elementwise_fma(wp[m - 2], q, QB);
                    }
                }
                hLA[s] = LA; hQA[s] = QA;
                hLB[s] = LB; hQB[s] = QB;

                // --- output row (11c + s - 10) completes now ---
                if (c > 0 || s == 10) {
                    vout(hLA, hQA, s);
                    vout(hLB, hQB, s);
                }
            }
        }

        // overwrite this wave's tile with the next chunk (in-order DS: safe)
        if (c < 3) store_chunk();
    }

    finish(lsum, wavesum, 8, tid, lane, w, acc_ws, ctr, out);
}

// =====================  ssim8: R26 exact (proven 42us fallback)  ============
__global__ __launch_bounds__(512, 1)
void ssim8(const float* __restrict__ x, const float* __restrict__ y,
           double* __restrict__ acc_ws, unsigned long long* __restrict__ ctr,
           float* __restrict__ out, GaussW gw) {
    extern __shared__ v4f dsm[];        // [8 waves][2 bufs][CHR][WUNITS]
    __shared__ float wavesum[8];

    const int tid  = threadIdx.x;
    const int w    = tid >> 6;          // wave id 0..7, owns a 64-col strip
    const int lane = tid & 63;
    const int c0 = w * 64;
    const int r0 = blockIdx.x * 64;
    const size_t img_off = (size_t)blockIdx.y * (IMG * IMG);
    const float* __restrict__ xb = x + img_off;
    const float* __restrict__ yb = y + img_off;

    v4f (*wtile)[CHR][WUNITS] =
        reinterpret_cast<v4f (*)[CHR][WUNITS]>(dsm + (size_t)w * (2 * CHR * WUNITS));

    const int ub = (lane + 3) >> 1;
    const int p  = (lane + 3) & 1;

    v2f wv2[12];
    #pragma unroll
    for (int m = 0; m < 12; ++m) {
        float lo = (m <= 10) ? gw.w[m] : 0.f;
        float hi = (m >= 1) ? gw.w[m - 1] : 0.f;
        float wm = p ? hi : lo;
        wv2[m][0] = wm; wv2[m][1] = wm;
    }
    v2f wp[11];
    #pragma unroll
    for (int k = 0; k < 11; ++k) { wp[k][0] = gw.w[k]; wp[k][1] = gw.w[k]; }

    float4 sxr[4], syr[4];

    auto load_chunk = [&](int c) {
        #pragma unroll
        for (int it = 0; it < 4; ++it) {
            int idx = lane + it * 64;
            int row = idx / WQUADS;
            int q   = idx - row * WQUADS;
            int gr = r0 - 5 + c * CHR + row;
            int gc = c0 - 8 + q * 4;
            float4 vx = make_float4(0.f, 0.f, 0.f, 0.f);
            float4 vy = vx;
            if (idx < NQ1 && (unsigned)gr < IMG && (unsigned)gc < IMG) {
                const float* px = xb + (size_t)gr * IMG + gc;
                const float* py = yb + (size_t)gr * IMG + gc;
                vx = *(const float4*)px;
                vy = *(const float4*)py;
            }
            sxr[it] = vx; syr[it] = vy;
        }
    };
    auto store_chunk = [&](int b) {
        #pragma unroll
        for (int it = 0; it < 4; ++it) {
            int idx = lane + it * 64;
            if (idx < NQ1) {
                int row = idx / WQUADS;
                int q   = idx - row * WQUADS;
                const float4 vx = sxr[it], vy = syr[it];
                wtile[b][row][q * 2]     = (v4f){vx.x + vy.x, vx.x - vy.x,
                                                 vx.y + vy.y, vx.y - vy.y};
                wtile[b][row][q * 2 + 1] = (v4f){vx.z + vy.z, vx.z - vy.z,
                                                 vx.w + vy.w, vx.w - vy.w};
            }
        }
    };

    v2f histL[11], histQ[11];
    float lsum = 0.f;
    const float C1x2 = 2e-4f, C2x2 = 1.8e-3f;

    load_chunk(0);
    store_chunk(0);

    #pragma unroll 1
    for (int c = 0; c < 7; ++c) {           // 7 chunks x 11 rows = 77 >= 74
        const int b = c & 1;
        if (c < 6) load_chunk(c + 1);

        #pragma unroll
        for (int s = 0; s < CHR; ++s) {
            if (!(c == 6 && s >= 8)) {      // m < 74
                v4f w6[6];
                #pragma unroll
                for (int i = 0; i < 6; ++i) w6[i] = wtile[b][s][ub + i];

                v2f hL = (v2f){0.f, 0.f};
                v2f hQ = (v2f){0.f, 0.f};
                #pragma unroll
                for (int m = 0; m < 12; ++m) {
                    v2f t = (m & 1) ? w6[m >> 1].zw : w6[m >> 1].xy;
                    hL = __builtin_elementwise_fma(wv2[m], t, hL);
                    v2f q = t * t;
                    hQ = __builtin_elementwise_fma(wv2[m], q, hQ);
                }
                histL[s] = hL; histQ[s] = hQ;

                if (c > 0 || s == 10) {
                    v2f aL = (v2f){0.f, 0.f};
                    v2f aQ = (v2f){0.f, 0.f};
                    #pragma unroll
                    for (int j = 0; j < 11; ++j) {
                        const int sl = (s + 1 + j) % 11;
                        aL = __builtin_elementwise_fma(wp[j], histL[sl], aL);
                        aQ = __builtin_elementwise_fma(wp[j], histQ[sl], aQ);
                    }
                    float a = aL[0] * aL[0], bq = aL[1] * aL[1];
                    float dm = a - bq;
                    float sm = a + bq;
                    float num = (dm + C1x2) * ((aQ[0] - aQ[1]) - dm + C2x2);
                    float den = (sm + C1x2) * ((aQ[0] + aQ[1]) - sm + C2x2);
                    lsum += num * __builtin_amdgcn_rcpf(den);
                }
            }
        }

        if (c < 6) store_chunk(b ^ 1);
    }

    finish(lsum, wavesum, 8, tid, lane, w, acc_ws, ctr, out);
}

extern "C" void kernel_launch(void* const* d_in, const int* in_sizes, int n_in,
                              void* d_out, int out_size, void* d_ws, size_t ws_size,
                              hipStream_t stream) {
    const float* x = (const float*)d_in[0];   // heatmap_clean
    const float* y = (const float*)d_in[1];   // heatmap_adv
    float* out = (float*)d_out;
    double* acc = (double*)d_ws;
    unsigned long long* ctr = (unsigned long long*)((char*)d_ws + 8);

    // One-time host-side setup (module queries, capture-safe): enable big
    // dynamic LDS on both kernels; pick ssim2c only if it is spill-free.
    static int use2c = -1;
    if (use2c < 0) {
        hipFuncSetAttribute(reinterpret_cast<const void*>(ssim8),
                            hipFuncAttributeMaxDynamicSharedMemorySize, LDS8_BYTES);
        hipFuncSetAttribute(reinterpret_cast<const void*>(ssim2c),
                            hipFuncAttributeMaxDynamicSharedMemorySize, LDS2_BYTES);
        hipFuncAttributes fa{};
        use2c = 0;
        if (hipFuncGetAttributes(&fa, reinterpret_cast<const void*>(ssim2c)) == hipSuccess)
            use2c = (fa.localSizeBytes == 0) ? 1 : 0;   // spill-free -> run 2-col
    }

    // zero the 16B of accumulator+counter state (capture-safe async memset)
    hipMemsetAsync(d_ws, 0, 16, stream);

    GaussW gw;
    double g[11], s = 0.0;
    for (int i = 0; i < 11; ++i) { double d = i - 5; g[i] = exp(-(d * d) / 4.5); s += g[i]; }
    for (int i = 0; i < 11; ++i) gw.w[i] = (float)(g[i] / s);

    dim3 grid(IMG / 64, 32);   // (8, 32) = 256 blocks = 1 per CU (both kernels)
    if (use2c)
        ssim2c<<<grid, 512, LDS2_BYTES, stream>>>(x, y, acc, ctr, out, gw);
    else
        ssim8<<<grid, 512, LDS8_BYTES, stream>>>(x, y, acc, ctr, out, gw);
}